// Round 1
// baseline (571.910 us; speedup 1.0000x reference)
//
#include <hip/hip_runtime.h>
#include <hip/hip_bf16.h>

typedef unsigned short u16;
typedef unsigned int u32;

#define M_DIM 8192   // B*S = 4*2048
#define K_DIM 4096   // I
#define N_DIM 4096   // O
#define GROUPS 64    // I / GROUP_SIZE

typedef __bf16 bf16x8 __attribute__((ext_vector_type(8)));
typedef float floatx4 __attribute__((ext_vector_type(4)));

__device__ __forceinline__ u16 f2bf(float f) {
  u32 u = __builtin_bit_cast(u32, f);
  u32 r = u + 0x7fffu + ((u >> 16) & 1u);   // RNE, inputs are finite
  return (u16)(r >> 16);
}

__device__ __forceinline__ void gload_lds16(const void* g, void* l) {
  __builtin_amdgcn_global_load_lds(
      (const __attribute__((address_space(1))) void*)g,
      (__attribute__((address_space(3))) void*)l, 16, 0, 0);
}

// ---------------- kernel 1: x' = bf16(x[perm]*cs[perm]) ----------------
__global__ __launch_bounds__(256) void prep_x(
    const float* __restrict__ x, const float* __restrict__ cs,
    const int* __restrict__ perm, u16* __restrict__ xb) {
  __shared__ float row[K_DIM];
  const size_t m = blockIdx.x;
  const float4* xr = (const float4*)(x + m * K_DIM);
  float4* r4 = (float4*)row;
  for (int j = threadIdx.x; j < K_DIM / 4; j += 256) r4[j] = xr[j];
  __syncthreads();
  u32* o = (u32*)(xb + m * K_DIM);
  for (int j = threadIdx.x; j < K_DIM / 2; j += 256) {
    int i0 = 2 * j;
    int p0 = perm[i0], p1 = perm[i0 + 1];
    float v0 = row[p0] * cs[p0];
    float v1 = row[p1] * cs[p1];
    u32 lo = f2bf(v0), hi = f2bf(v1);
    o[j] = lo | (hi << 16);
  }
}

// ---------------- kernel 2: W' = bf16(nib*scale + zero) ----------------
__global__ __launch_bounds__(256) void prep_w(
    const u32* __restrict__ qw, const float* __restrict__ scales,
    const float* __restrict__ zeros, u16* __restrict__ wb) {
  int w = blockIdx.x * 256 + threadIdx.x;   // word index, < N_DIM*512
  u32 q = qw[w];
  int o = w >> 9;               // / (K_DIM/8)
  int g = (w >> 3) & (GROUPS - 1);
  float s = scales[o * GROUPS + g];
  float z = zeros[o * GROUPS + g];
  u32 p[4];
#pragma unroll
  for (int j = 0; j < 4; ++j) {
    float f0 = (float)((q >> (8 * j)) & 15u) * s + z;
    float f1 = (float)((q >> (8 * j + 4)) & 15u) * s + z;
    p[j] = (u32)f2bf(f0) | ((u32)f2bf(f1) << 16);
  }
  uint4 v = make_uint4(p[0], p[1], p[2], p[3]);
  ((uint4*)wb)[w] = v;   // 16B aligned: word w -> 8 bf16
}

// ---------------- kernel 3: out = Xb @ Wb^T + bias ----------------
// A: [M][K] bf16, B: [N][K] bf16, out: [M][N] fp32
__global__ __launch_bounds__(256) void gemm_bt(
    const u16* __restrict__ A, const u16* __restrict__ B,
    const float* __restrict__ bias, float* __restrict__ out) {
  __shared__ __align__(16) u16 As[128 * 32];
  __shared__ __align__(16) u16 Bs[128 * 32];
  const int tid = threadIdx.x;
  const int lane = tid & 63;
  const int wave = tid >> 6;
  const int wm = wave >> 1, wn = wave & 1;
  const int q = lane >> 4, lr = lane & 15;
  const int blockN = blockIdx.x * 128;
  const int blockM = blockIdx.y * 128;

  floatx4 acc[4][4];
#pragma unroll
  for (int i = 0; i < 4; ++i)
#pragma unroll
    for (int j = 0; j < 4; ++j) acc[i][j] = (floatx4)0.0f;

  const char* Abase = (const char*)(A + (size_t)blockM * K_DIM);
  const char* Bbase = (const char*)(B + (size_t)blockN * K_DIM);

  // 16B chunk c: row = c>>2, kchunk = c&3.  LDS dest = chunk*16 bytes
  // (wave-uniform base + lane*16: c = j*256 + wave*64 + lane)
  const int c0 = tid, c1 = 256 + tid;
  const int r0 = c0 >> 2, kc0 = c0 & 3;
  const int r1 = c1 >> 2, kc1 = c1 & 3;
  const size_t rowb = (size_t)K_DIM * 2;

  for (int kt = 0; kt < K_DIM / 32; ++kt) {
    const size_t koff = (size_t)kt * 64;
    gload_lds16(Abase + (size_t)r0 * rowb + koff + kc0 * 16, &As[c0 * 8]);
    gload_lds16(Abase + (size_t)r1 * rowb + koff + kc1 * 16, &As[c1 * 8]);
    gload_lds16(Bbase + (size_t)r0 * rowb + koff + kc0 * 16, &Bs[c0 * 8]);
    gload_lds16(Bbase + (size_t)r1 * rowb + koff + kc1 * 16, &Bs[c1 * 8]);
    __syncthreads();   // compiler emits s_waitcnt vmcnt(0) before s_barrier

    bf16x8 af[4], bfr[4];
#pragma unroll
    for (int mi = 0; mi < 4; ++mi)
      af[mi] = *(const bf16x8*)&As[(wm * 64 + mi * 16 + lr) * 32 + q * 8];
#pragma unroll
    for (int ni = 0; ni < 4; ++ni)
      bfr[ni] = *(const bf16x8*)&Bs[(wn * 64 + ni * 16 + lr) * 32 + q * 8];
#pragma unroll
    for (int mi = 0; mi < 4; ++mi)
#pragma unroll
      for (int ni = 0; ni < 4; ++ni)
        acc[mi][ni] = __builtin_amdgcn_mfma_f32_16x16x32_bf16(
            af[mi], bfr[ni], acc[mi][ni], 0, 0, 0);
    __syncthreads();
  }

  // epilogue: C/D layout col = lane&15, row = quad*4 + reg
#pragma unroll
  for (int ni = 0; ni < 4; ++ni) {
    const int col = blockN + wn * 64 + ni * 16 + lr;
    const float bv = bias[col];
#pragma unroll
    for (int mi = 0; mi < 4; ++mi) {
      const int row0 = blockM + wm * 64 + mi * 16 + q * 4;
#pragma unroll
      for (int r = 0; r < 4; ++r)
        out[(size_t)(row0 + r) * N_DIM + col] = acc[mi][ni][r] + bv;
    }
  }
}

extern "C" void kernel_launch(void* const* d_in, const int* in_sizes, int n_in,
                              void* d_out, int out_size, void* d_ws, size_t ws_size,
                              hipStream_t stream) {
  const float* x      = (const float*)d_in[0];
  const float* cs     = (const float*)d_in[1];
  const u32*   qw     = (const u32*)d_in[2];
  const int*   perm   = (const int*)d_in[3];
  const float* scales = (const float*)d_in[4];
  const float* zeros  = (const float*)d_in[5];
  const float* bias   = (const float*)d_in[6];
  float* out = (float*)d_out;

  u16* xb = (u16*)d_ws;                          // 64 MiB: M*K bf16
  u16* wb = xb + (size_t)M_DIM * K_DIM;          // 32 MiB: N*K bf16

  hipLaunchKernelGGL(prep_x, dim3(M_DIM), dim3(256), 0, stream, x, cs, perm, xb);
  hipLaunchKernelGGL(prep_w, dim3(N_DIM * 512 / 256), dim3(256), 0, stream,
                     qw, scales, zeros, wb);
  hipLaunchKernelGGL(gemm_bt, dim3(N_DIM / 128, M_DIM / 128), dim3(256), 0,
                     stream, xb, wb, bias, out);
}

// Round 2
// 539.901 us; speedup vs baseline: 1.0593x; 1.0593x over previous
//
#include <hip/hip_runtime.h>
#include <hip/hip_bf16.h>

typedef unsigned short u16;
typedef unsigned int u32;

#define M_DIM 8192   // B*S = 4*2048
#define K_DIM 4096   // I
#define N_DIM 4096   // O
#define GROUPS 64    // I / GROUP_SIZE

typedef __bf16 bf16x8 __attribute__((ext_vector_type(8)));
typedef float floatx4 __attribute__((ext_vector_type(4)));

__device__ __forceinline__ u16 f2bf(float f) {
  u32 u = __builtin_bit_cast(u32, f);
  u32 r = u + 0x7fffu + ((u >> 16) & 1u);   // RNE, inputs are finite
  return (u16)(r >> 16);
}

__device__ __forceinline__ void gload_lds16(const void* g, void* l) {
  __builtin_amdgcn_global_load_lds(
      (const __attribute__((address_space(1))) void*)g,
      (__attribute__((address_space(3))) void*)l, 16, 0, 0);
}

// ---------------- kernel 1: xb[m][p] = bf16(x[m][p]*cs[p]) ----------------
// Pure elementwise, no gathers (permutation folded into weights).
__global__ __launch_bounds__(256) void prep_x(
    const float* __restrict__ x, const float* __restrict__ cs,
    u16* __restrict__ xb) {
  const size_t total = (size_t)M_DIM * K_DIM / 4;   // float4 count
  const size_t stride = (size_t)gridDim.x * 256;
  for (size_t idx = (size_t)blockIdx.x * 256 + threadIdx.x; idx < total;
       idx += stride) {
    float4 v = ((const float4*)x)[idx];
    float4 c = ((const float4*)cs)[idx & (K_DIM / 4 - 1)];
    u32 lo = (u32)f2bf(v.x * c.x) | ((u32)f2bf(v.y * c.y) << 16);
    u32 hi = (u32)f2bf(v.z * c.z) | ((u32)f2bf(v.w * c.w) << 16);
    ((uint2*)xb)[idx] = make_uint2(lo, hi);
  }
}

// ------- kernel 2: W2[o][perm[j]] = bf16(nib_j(qw[o])*scale + zero) -------
// One block per output row o; scatter through an 8 KB LDS row buffer,
// then write out coalesced.
__global__ __launch_bounds__(256) void prep_w2(
    const u32* __restrict__ qw, const int* __restrict__ perm,
    const float* __restrict__ scales, const float* __restrict__ zeros,
    u16* __restrict__ wb) {
  __shared__ u16 rowbuf[K_DIM];   // 8 KB
  const int o = blockIdx.x;
  const u32* qrow = qw + (size_t)o * (K_DIM / 8);
#pragma unroll
  for (int t = threadIdx.x; t < K_DIM / 8; t += 256) {
    u32 q = qrow[t];
    int j0 = t * 8;
    int g = t >> 3;   // 8 words per group of 64
    float s = scales[o * GROUPS + g];
    float z = zeros[o * GROUPS + g];
#pragma unroll
    for (int n = 0; n < 8; ++n) {
      float v = (float)((q >> (4 * n)) & 15u) * s + z;
      rowbuf[perm[j0 + n]] = f2bf(v);
    }
  }
  __syncthreads();
  uint4* dst = (uint4*)(wb + (size_t)o * K_DIM);
  const uint4* src = (const uint4*)rowbuf;
  for (int t = threadIdx.x; t < K_DIM / 8; t += 256) dst[t] = src[t];
}

// ---------------- kernel 3: out = Xb @ Wb^T + bias ----------------
// A: [M][K] bf16, B: [N][K] bf16, out: [M][N] fp32
// LDS layout: row r of a tile holds its four 16B k-chunks XOR-swizzled:
// physical slot s holds global chunk s ^ ((r>>1)&3).  Swizzle is applied on
// the global source address (LDS dest must stay uniform+lane*16 for
// global_load_lds); reads un-swizzle with q ^ ((lr>>1)&3).
__global__ __launch_bounds__(256) void gemm_bt(
    const u16* __restrict__ A, const u16* __restrict__ B,
    const float* __restrict__ bias, float* __restrict__ out) {
  __shared__ __align__(16) u16 As[128 * 32];
  __shared__ __align__(16) u16 Bs[128 * 32];
  const int tid = threadIdx.x;
  const int lane = tid & 63;
  const int wave = tid >> 6;
  const int wm = wave >> 1, wn = wave & 1;
  const int q = lane >> 4, lr = lane & 15;
  const int qs = q ^ ((lr >> 1) & 3);   // swizzled k-chunk slot for reads
  const int blockN = blockIdx.x * 128;
  const int blockM = blockIdx.y * 128;

  floatx4 acc[4][4];
#pragma unroll
  for (int i = 0; i < 4; ++i)
#pragma unroll
    for (int j = 0; j < 4; ++j) acc[i][j] = (floatx4)0.0f;

  const char* Abase = (const char*)(A + (size_t)blockM * K_DIM);
  const char* Bbase = (const char*)(B + (size_t)blockN * K_DIM);

  // 16B chunk slot c: row = c>>2, slot = c&3 -> fetch global chunk slot^((r>>1)&3)
  const int c0 = tid, c1 = 256 + tid;
  const int r0 = c0 >> 2, kc0 = (c0 & 3) ^ ((c0 >> 3) & 3);
  const int r1 = c1 >> 2, kc1 = (c1 & 3) ^ ((c1 >> 3) & 3);
  const size_t rowb = (size_t)K_DIM * 2;

  for (int kt = 0; kt < K_DIM / 32; ++kt) {
    const size_t koff = (size_t)kt * 64;
    gload_lds16(Abase + (size_t)r0 * rowb + koff + kc0 * 16, &As[c0 * 8]);
    gload_lds16(Abase + (size_t)r1 * rowb + koff + kc1 * 16, &As[c1 * 8]);
    gload_lds16(Bbase + (size_t)r0 * rowb + koff + kc0 * 16, &Bs[c0 * 8]);
    gload_lds16(Bbase + (size_t)r1 * rowb + koff + kc1 * 16, &Bs[c1 * 8]);
    __syncthreads();

    bf16x8 af[4], bfr[4];
#pragma unroll
    for (int mi = 0; mi < 4; ++mi)
      af[mi] = *(const bf16x8*)&As[(wm * 64 + mi * 16 + lr) * 32 + qs * 8];
#pragma unroll
    for (int ni = 0; ni < 4; ++ni)
      bfr[ni] = *(const bf16x8*)&Bs[(wn * 64 + ni * 16 + lr) * 32 + qs * 8];
#pragma unroll
    for (int mi = 0; mi < 4; ++mi)
#pragma unroll
      for (int ni = 0; ni < 4; ++ni)
        acc[mi][ni] = __builtin_amdgcn_mfma_f32_16x16x32_bf16(
            af[mi], bfr[ni], acc[mi][ni], 0, 0, 0);
    __syncthreads();
  }

  // epilogue: C/D layout col = lane&15, row = quad*4 + reg
#pragma unroll
  for (int ni = 0; ni < 4; ++ni) {
    const int col = blockN + wn * 64 + ni * 16 + lr;
    const float bv = bias[col];
#pragma unroll
    for (int mi = 0; mi < 4; ++mi) {
      const int row0 = blockM + wm * 64 + mi * 16 + q * 4;
#pragma unroll
      for (int r = 0; r < 4; ++r)
        out[(size_t)(row0 + r) * N_DIM + col] = acc[mi][ni][r] + bv;
    }
  }
}

extern "C" void kernel_launch(void* const* d_in, const int* in_sizes, int n_in,
                              void* d_out, int out_size, void* d_ws, size_t ws_size,
                              hipStream_t stream) {
  const float* x      = (const float*)d_in[0];
  const float* cs     = (const float*)d_in[1];
  const u32*   qw     = (const u32*)d_in[2];
  const int*   perm   = (const int*)d_in[3];
  const float* scales = (const float*)d_in[4];
  const float* zeros  = (const float*)d_in[5];
  const float* bias   = (const float*)d_in[6];
  float* out = (float*)d_out;

  u16* xb = (u16*)d_ws;                          // 64 MiB: M*K bf16
  u16* wb = xb + (size_t)M_DIM * K_DIM;          // 32 MiB: N*K bf16 (permuted cols)

  hipLaunchKernelGGL(prep_x, dim3(8192), dim3(256), 0, stream, x, cs, xb);
  hipLaunchKernelGGL(prep_w2, dim3(N_DIM), dim3(256), 0, stream,
                     qw, perm, scales, zeros, wb);
  hipLaunchKernelGGL(gemm_bt, dim3(N_DIM / 128, M_DIM / 128), dim3(256), 0,
                     stream, xb, wb, bias, out);
}